// Round 1
// baseline (26.642 us; speedup 1.0000x reference)
//
#include <hip/hip_runtime.h>
#include <math.h>

#define N_STEPS 8
#define BATCH   128
#define VOCAB   32000
#define NROWS   (N_STEPS * BATCH)   // 1024
#define V4      (VOCAB / 4)         // 8000 float4 per row

// One block per (step, batch) row: streaming online logsumexp over 32000 f32,
// then write p[row] * (lse - y_pred[row, y_true[b]-1]) to ws[row].
__global__ __launch_bounds__(256) void crl_row_lse_kernel(
    const float* __restrict__ p,
    const float* __restrict__ y_pred,
    const int*   __restrict__ y_true,
    float*       __restrict__ ws)
{
    const int row = blockIdx.x;          // row = n*BATCH + b
    const int tid = threadIdx.x;
    const float4* rp = reinterpret_cast<const float4*>(y_pred + (size_t)row * VOCAB);

    // Branchless online (max, sum-of-exp) per thread over strided float4s.
    float m = -INFINITY;
    float s = 0.0f;
    for (int i = tid; i < V4; i += 256) {
        float4 v  = rp[i];
        float  m4 = fmaxf(fmaxf(v.x, v.y), fmaxf(v.z, v.w));
        float  mn = fmaxf(m, m4);
        s = s * __expf(m - mn)
          + __expf(v.x - mn) + __expf(v.y - mn)
          + __expf(v.z - mn) + __expf(v.w - mn);
        m = mn;
    }

    // Wave (64-lane) butterfly reduction of (m, s) pairs.
    #pragma unroll
    for (int off = 32; off > 0; off >>= 1) {
        float mo = __shfl_xor(m, off, 64);
        float so = __shfl_xor(s, off, 64);
        float mn = fmaxf(m, mo);
        s = s * __expf(m - mn) + so * __expf(mo - mn);
        m = mn;
    }

    // Merge the 4 waves via LDS.
    __shared__ float sm[4];
    __shared__ float ss[4];
    const int wave = tid >> 6;
    const int lane = tid & 63;
    if (lane == 0) { sm[wave] = m; ss[wave] = s; }
    __syncthreads();

    if (tid == 0) {
        float M = sm[0], S = ss[0];
        #pragma unroll
        for (int w = 1; w < 4; ++w) {
            float mo = sm[w], so = ss[w];
            float mn = fmaxf(M, mo);
            S = S * __expf(M - mn) + so * __expf(mo - mn);
            M = mn;
        }
        const float lse = M + logf(S);
        const int   b   = row & (BATCH - 1);
        const int   t   = y_true[b] - 1;                 // 0..31999
        const float g   = y_pred[(size_t)row * VOCAB + t];
        ws[row] = p[row] * (lse - g);
    }
}

// Deterministic final reduction of 1024 partials -> scalar / BATCH.
__global__ __launch_bounds__(256) void crl_reduce_kernel(
    const float* __restrict__ ws,
    float*       __restrict__ out)
{
    const int tid = threadIdx.x;
    float v = ws[tid] + ws[tid + 256] + ws[tid + 512] + ws[tid + 768];
    #pragma unroll
    for (int off = 32; off > 0; off >>= 1)
        v += __shfl_xor(v, off, 64);

    __shared__ float sv[4];
    if ((tid & 63) == 0) sv[tid >> 6] = v;
    __syncthreads();
    if (tid == 0)
        out[0] = (sv[0] + sv[1] + sv[2] + sv[3]) * (1.0f / (float)BATCH);
}

extern "C" void kernel_launch(void* const* d_in, const int* in_sizes, int n_in,
                              void* d_out, int out_size, void* d_ws, size_t ws_size,
                              hipStream_t stream) {
    const float* p      = (const float*)d_in[0];   // (8,128) f32
    const float* y_pred = (const float*)d_in[1];   // (8,128,32000) f32
    const int*   y_true = (const int*)d_in[2];     // (128,) int
    // d_in[3] = pad_id (unused by reference)

    float* ws  = (float*)d_ws;    // 1024 f32 partials
    float* out = (float*)d_out;   // 1 f32

    crl_row_lse_kernel<<<NROWS, 256, 0, stream>>>(p, y_pred, y_true, ws);
    crl_reduce_kernel<<<1, 256, 0, stream>>>(ws, out);
}

// Round 2
// 26.582 us; speedup vs baseline: 1.0023x; 1.0023x over previous
//
#include <hip/hip_runtime.h>
#include <math.h>

#define N_STEPS 8
#define BATCH   128
#define VOCAB   32000
#define NROWS   (N_STEPS * BATCH)   // 1024
#define V4      (VOCAB / 4)         // 8000 float4 per row
#define THREADS 512                 // 8 waves/block * 4 blocks/CU = 32 waves/CU (full occupancy)

// One block per (step, batch) row: streaming online logsumexp over 32000 f32,
// then write p[row] * (lse - y_pred[row, y_true[b]-1]) to ws[row].
__global__ __launch_bounds__(THREADS) void crl_row_lse_kernel(
    const float* __restrict__ p,
    const float* __restrict__ y_pred,
    const int*   __restrict__ y_true,
    float*       __restrict__ ws)
{
    const int row = blockIdx.x;          // row = n*BATCH + b
    const int tid = threadIdx.x;
    const float4* rp = reinterpret_cast<const float4*>(y_pred + (size_t)row * VOCAB);

    // Hoist the scalar gather: its dependent-load latency hides under the loop.
    float pv = 0.0f, gv = 0.0f;
    if (tid == 0) {
        const int b = row & (BATCH - 1);
        const int t = y_true[b] - 1;                 // 0..31999
        gv = y_pred[(size_t)row * VOCAB + t];
        pv = p[row];
    }

    // Branchless online (max, sum-of-exp) per thread over strided float4s.
    float m = -INFINITY;
    float s = 0.0f;
    for (int i = tid; i < V4; i += THREADS) {
        float4 v  = rp[i];
        float  m4 = fmaxf(fmaxf(v.x, v.y), fmaxf(v.z, v.w));
        float  mn = fmaxf(m, m4);
        s = s * __expf(m - mn)
          + __expf(v.x - mn) + __expf(v.y - mn)
          + __expf(v.z - mn) + __expf(v.w - mn);
        m = mn;
    }

    // Wave (64-lane) butterfly reduction of (m, s) pairs.
    #pragma unroll
    for (int off = 32; off > 0; off >>= 1) {
        float mo = __shfl_xor(m, off, 64);
        float so = __shfl_xor(s, off, 64);
        float mn = fmaxf(m, mo);
        s = s * __expf(m - mn) + so * __expf(mo - mn);
        m = mn;
    }

    // Merge the 8 waves via LDS.
    __shared__ float sm[THREADS / 64];
    __shared__ float ss[THREADS / 64];
    const int wave = tid >> 6;
    const int lane = tid & 63;
    if (lane == 0) { sm[wave] = m; ss[wave] = s; }
    __syncthreads();

    if (tid == 0) {
        float M = sm[0], S = ss[0];
        #pragma unroll
        for (int w = 1; w < THREADS / 64; ++w) {
            float mo = sm[w], so = ss[w];
            float mn = fmaxf(M, mo);
            S = S * __expf(M - mn) + so * __expf(mo - mn);
            M = mn;
        }
        const float lse = M + logf(S);
        ws[row] = pv * (lse - gv);
    }
}

// Deterministic final reduction of 1024 partials -> scalar / BATCH.
__global__ __launch_bounds__(256) void crl_reduce_kernel(
    const float* __restrict__ ws,
    float*       __restrict__ out)
{
    const int tid = threadIdx.x;
    float v = ws[tid] + ws[tid + 256] + ws[tid + 512] + ws[tid + 768];
    #pragma unroll
    for (int off = 32; off > 0; off >>= 1)
        v += __shfl_xor(v, off, 64);

    __shared__ float sv[4];
    if ((tid & 63) == 0) sv[tid >> 6] = v;
    __syncthreads();
    if (tid == 0)
        out[0] = (sv[0] + sv[1] + sv[2] + sv[3]) * (1.0f / (float)BATCH);
}

extern "C" void kernel_launch(void* const* d_in, const int* in_sizes, int n_in,
                              void* d_out, int out_size, void* d_ws, size_t ws_size,
                              hipStream_t stream) {
    const float* p      = (const float*)d_in[0];   // (8,128) f32
    const float* y_pred = (const float*)d_in[1];   // (8,128,32000) f32
    const int*   y_true = (const int*)d_in[2];     // (128,) int
    // d_in[3] = pad_id (unused by reference)

    float* ws  = (float*)d_ws;    // 1024 f32 partials
    float* out = (float*)d_out;   // 1 f32

    crl_row_lse_kernel<<<NROWS, THREADS, 0, stream>>>(p, y_pred, y_true, ws);
    crl_reduce_kernel<<<1, 256, 0, stream>>>(ws, out);
}